// Round 4
// baseline (2580.927 us; speedup 1.0000x reference)
//
#include <hip/hip_runtime.h>
#include <cstdint>
#include <cstddef>

typedef _Float16 half8 __attribute__((ext_vector_type(8)));
typedef float f32x4 __attribute__((ext_vector_type(4)));

#define S_LEN 2048
#define HDIM  256
#define BATCH 64
#define LROW  264   // LDS row stride in f16 (dword stride 132 ≡ 4 mod 32)

__device__ __forceinline__ float tanh_fast(float x) {
    // tanh(x) = 1 - 2/(e^{2x}+1); e^{2x} = 2^{x*2*log2(e)}
    float e = exp2f(x * 2.8853900817779268f);
    return 1.0f - 2.0f / (e + 1.0f);
}

// ---------------------------------------------------------------------------
// Kernel A: xp[m, h] = sum_i x[m, i] * Wxh[h, i] + bxh[h]   (unchanged)
// ---------------------------------------------------------------------------
__global__ void __launch_bounds__(256) xp_gemm(
    const float* __restrict__ x, const float* __restrict__ Wxh,
    const float* __restrict__ bxh, float* __restrict__ out) {
    __shared__ float As[32][68];
    __shared__ float Bs[32][68];

    const int tid = threadIdx.x;
    const int tx = tid & 15;
    const int ty = tid >> 4;
    const size_t m0 = (size_t)blockIdx.x * 64;
    const int n0 = blockIdx.y * 64;

    const int r = tid >> 3;
    const int c = (tid & 7) * 4;

    float bj[4];
#pragma unroll
    for (int j = 0; j < 4; j++) bj[j] = bxh[n0 + tx * 4 + j];

    float acc[4][4] = {};

    for (int k0 = 0; k0 < 256; k0 += 32) {
        float4 a0 = *(const float4*)&x[(m0 + r) * 256 + k0 + c];
        float4 a1 = *(const float4*)&x[(m0 + r + 32) * 256 + k0 + c];
        float4 b0 = *(const float4*)&Wxh[(size_t)(n0 + r) * 256 + k0 + c];
        float4 b1 = *(const float4*)&Wxh[(size_t)(n0 + r + 32) * 256 + k0 + c];

        __syncthreads();
        As[c + 0][r] = a0.x; As[c + 1][r] = a0.y; As[c + 2][r] = a0.z; As[c + 3][r] = a0.w;
        As[c + 0][r + 32] = a1.x; As[c + 1][r + 32] = a1.y; As[c + 2][r + 32] = a1.z; As[c + 3][r + 32] = a1.w;
        Bs[c + 0][r] = b0.x; Bs[c + 1][r] = b0.y; Bs[c + 2][r] = b0.z; Bs[c + 3][r] = b0.w;
        Bs[c + 0][r + 32] = b1.x; Bs[c + 1][r + 32] = b1.y; Bs[c + 2][r + 32] = b1.z; Bs[c + 3][r + 32] = b1.w;
        __syncthreads();

#pragma unroll
        for (int kk = 0; kk < 32; kk++) {
            float4 av = *(const float4*)&As[kk][ty * 4];
            float4 bv = *(const float4*)&Bs[kk][tx * 4];
            float aa[4] = {av.x, av.y, av.z, av.w};
            float bb[4] = {bv.x, bv.y, bv.z, bv.w};
#pragma unroll
            for (int i = 0; i < 4; i++)
#pragma unroll
                for (int j = 0; j < 4; j++)
                    acc[i][j] = fmaf(aa[i], bb[j], acc[i][j]);
        }
    }

#pragma unroll
    for (int i = 0; i < 4; i++) {
        float4 o;
        o.x = acc[i][0] + bj[0];
        o.y = acc[i][1] + bj[1];
        o.z = acc[i][2] + bj[2];
        o.w = acc[i][3] + bj[3];
        *(float4*)&out[(m0 + ty * 4 + i) * 256 + n0 + tx * 4] = o;
    }
}

// ---------------------------------------------------------------------------
// Kernel B: MFMA recurrence, lean-VALU version. 4 WGs x 512 threads (8 waves).
// Wave w owns cols [w*32, w*32+32) as two 16-col tiles. W_hh B-fragments in
// VGPRs (one-time). h_t in f16 LDS, double-buffered. All global accesses via
// SGPR-base + 32-bit byte-offset VGPRs advanced by immediates; LDS via
// precomputed base pointers + offset immediates. xp prefetched 2 steps ahead.
// Fragment maps identical to R3 (verified): A elem j = h[c][kt*32+8g+j],
// B elem j = Whh[n][kt*32+8g+j], C/D: col=lane&15, row=4*(lane>>4)+reg.
// ---------------------------------------------------------------------------
__global__ void __launch_bounds__(512, 2) rnn_mfma(
    const float* __restrict__ Whh, const float* __restrict__ bhh,
    float* __restrict__ out) {
    const int wg = blockIdx.x;      // 0..3
    const int t = threadIdx.x;
    const int w = t >> 6;           // wave 0..7
    const int l = t & 63;
    const int c = l & 15;           // col within tile / A row
    const int g = l >> 4;           // k-group 0..3
    const int n0 = w * 32 + c;      // tile0 col; tile1 = n0+16

    __shared__ _Float16 hls[2][16][LROW];

    // ---- one-time: W_hh B-fragments into registers (f16) ----
    half8 wf0[8], wf1[8];
    {
        const float* wr0 = Whh + (size_t)n0 * HDIM;
        const float* wr1 = Whh + (size_t)(n0 + 16) * HDIM;
#pragma unroll
        for (int kt = 0; kt < 8; kt++) {
            float4 u = *(const float4*)&wr0[kt * 32 + 8 * g];
            float4 v = *(const float4*)&wr0[kt * 32 + 8 * g + 4];
            half8 f;
            f[0] = (_Float16)u.x; f[1] = (_Float16)u.y;
            f[2] = (_Float16)u.z; f[3] = (_Float16)u.w;
            f[4] = (_Float16)v.x; f[5] = (_Float16)v.y;
            f[6] = (_Float16)v.z; f[7] = (_Float16)v.w;
            wf0[kt] = f;
            u = *(const float4*)&wr1[kt * 32 + 8 * g];
            v = *(const float4*)&wr1[kt * 32 + 8 * g + 4];
            f[0] = (_Float16)u.x; f[1] = (_Float16)u.y;
            f[2] = (_Float16)u.z; f[3] = (_Float16)u.w;
            f[4] = (_Float16)v.x; f[5] = (_Float16)v.y;
            f[6] = (_Float16)v.z; f[7] = (_Float16)v.w;
            wf1[kt] = f;
        }
    }
    const float bv0 = bhh[n0];
    const float bv1 = bhh[n0 + 16];

    // ---- zero h_0 (both buffers, incl. padding) ----
    for (int i = t; i < 2 * 16 * LROW; i += 512) (&hls[0][0][0])[i] = (_Float16)0.f;

    // ---- global access bases: SGPR base `out`, per-lane 32-bit byte offsets
    const char* ob = (const char*)out;
    uint32_t boffA[4], boffB[4];
#pragma unroll
    for (int r = 0; r < 4; r++) {
        boffA[r] = (uint32_t)((((size_t)(wg * 16 + 4 * g + r) * S_LEN * HDIM) + n0) * 4u);
        boffB[r] = boffA[r] + HDIM * 4;
    }

    // ---- prologue: xp for s=0 (set A) and s=1 (set B) ----
    f32x4 xA0, xA1, xB0, xB1;
#pragma unroll
    for (int r = 0; r < 4; r++) {
        xA0[r] = *(const float*)(ob + boffA[r]);
        xA1[r] = *(const float*)(ob + boffA[r] + 64);
        xB0[r] = *(const float*)(ob + boffB[r]);
        xB1[r] = *(const float*)(ob + boffB[r] + 64);
    }

    // ---- LDS base pointers (phase-even reads buf0/writes buf1; odd swaps)
    const _Float16* rdA = &hls[0][c][8 * g];
    const _Float16* rdB = &hls[1][c][8 * g];
    _Float16* wrA = &hls[1][4 * g][n0];
    _Float16* wrB = &hls[0][4 * g][n0];

    float* hl = out + (size_t)BATCH * S_LEN * HDIM;

    __syncthreads();

    auto phase = [&](int s, f32x4& xq0, f32x4& xq1, uint32_t (&boff)[4],
                     const _Float16* rb, _Float16* wb) {
        // A-fragments from LDS (offset immediates kt*64 B)
        half8 af[8];
#pragma unroll
        for (int kt = 0; kt < 8; kt++)
            af[kt] = *(const half8*)(rb + kt * 32);

        // seed accumulators with xp + bias
        f32x4 a0, a1;
#pragma unroll
        for (int r = 0; r < 4; r++) {
            a0[r] = xq0[r] + bv0;
            a1[r] = xq1[r] + bv1;
        }

        // prefetch xp for step s+2 (row at boff+2048); uniform guard
        if (s + 2 < S_LEN) {
#pragma unroll
            for (int r = 0; r < 4; r++) {
                xq0[r] = *(const float*)(ob + boff[r] + 2048);
                xq1[r] = *(const float*)(ob + boff[r] + 2048 + 64);
            }
        }

#pragma unroll
        for (int kt = 0; kt < 8; kt++) {
            a0 = __builtin_amdgcn_mfma_f32_16x16x32_f16(af[kt], wf0[kt], a0, 0, 0, 0);
            a1 = __builtin_amdgcn_mfma_f32_16x16x32_f16(af[kt], wf1[kt], a1, 0, 0, 0);
        }

        // epilogue: tanh, h_seq store (imm 0/64), f16 h post (imm r*528/+32)
        float vv0[4], vv1[4];
#pragma unroll
        for (int r = 0; r < 4; r++) {
            float v0 = tanh_fast(a0[r]);
            float v1 = tanh_fast(a1[r]);
            vv0[r] = v0; vv1[r] = v1;
            *(float*)((char*)ob + boff[r]) = v0;
            *(float*)((char*)ob + boff[r] + 64) = v1;
            wb[r * LROW] = (_Float16)v0;
            wb[r * LROW + 16] = (_Float16)v1;
        }
        if (s == S_LEN - 1) {
#pragma unroll
            for (int r = 0; r < 4; r++) {
                hl[(wg * 16 + 4 * g + r) * HDIM + n0] = vv0[r];
                hl[(wg * 16 + 4 * g + r) * HDIM + n0 + 16] = vv1[r];
            }
        }
#pragma unroll
        for (int r = 0; r < 4; r++) boff[r] += 2 * HDIM * 4;
        __syncthreads();
    };

    for (int s = 0; s < S_LEN; s += 2) {
        phase(s, xA0, xA1, boffA, rdA, wrA);
        phase(s + 1, xB0, xB1, boffB, rdB, wrB);
    }
}

extern "C" void kernel_launch(void* const* d_in, const int* in_sizes, int n_in,
                              void* d_out, int out_size, void* d_ws, size_t ws_size,
                              hipStream_t stream) {
    const float* x   = (const float*)d_in[0];
    const float* Wxh = (const float*)d_in[1];
    const float* bxh = (const float*)d_in[2];
    const float* Whh = (const float*)d_in[3];
    const float* bhh = (const float*)d_in[4];
    float* out = (float*)d_out;

    dim3 gridA(131072 / 64, 256 / 64);  // (2048, 4)
    xp_gemm<<<gridA, 256, 0, stream>>>(x, Wxh, bxh, out);
    rnn_mfma<<<4, 512, 0, stream>>>(Whh, bhh, out);
}